// Round 4
// baseline (197.162 us; speedup 1.0000x reference)
//
#include <hip/hip_runtime.h>
#include <math.h>

#define BB_   2
#define CIN_  256
#define NTOK_ 2048
#define FF_   512
#define COUT_ 256
#define NH_   8
#define DH_   64
#define HW_   128
#define BNEPS_ 1e-5f
#define SCALE_LOG2_ 0.09016844005556021f  /* log2(e)/16 */

typedef __attribute__((ext_vector_type(8))) short short8;
typedef __attribute__((ext_vector_type(4))) float f32x4;

__device__ inline unsigned short f2bf(float f) {
  union { float f; unsigned u; } v; v.f = f;
  unsigned r = (v.u + 0x7FFF + ((v.u >> 16) & 1)) >> 16;  // RNE
  return (unsigned short)r;
}
__device__ inline float bf2f(unsigned short u) {
  union { unsigned u; float f; } v; v.u = ((unsigned)u) << 16;
  return v.f;
}

// ---------------------------------------------------------------------------
// Kernel 0: prep — x fp32 [b][c][n] -> xT bf16 [b][n][c] (LDS transpose);
// weights fp32 -> bf16 flat; zero BN stats.
// ---------------------------------------------------------------------------
__global__ __launch_bounds__(256) void prep_kernel(
    const float* __restrict__ x, const float* __restrict__ WK,
    const float* __restrict__ WQ, const float* __restrict__ WV,
    const float* __restrict__ Wo, unsigned short* __restrict__ xT,
    unsigned short* __restrict__ Wkb, unsigned short* __restrict__ Wqb,
    unsigned short* __restrict__ Wvb, unsigned short* __restrict__ Wob,
    float* __restrict__ stats) {
  __shared__ float T[64 * 65];
  const int tid = threadIdx.x;
  const int bid = blockIdx.x;
  if (bid < 256) {
    const int b = bid >> 7;
    const int rem = bid & 127;
    const int n0 = (rem >> 2) * 64;
    const int c0 = (rem & 3) * 64;
#pragma unroll
    for (int p = 0; p < 4; ++p) {
      const int idx = tid + 256 * p;
      const int row = idx >> 4, col = (idx & 15) * 4;
      const float4 v =
          *(const float4*)(x + (size_t)(b * CIN_ + c0 + row) * NTOK_ + n0 + col);
      T[row * 65 + col + 0] = v.x; T[row * 65 + col + 1] = v.y;
      T[row * 65 + col + 2] = v.z; T[row * 65 + col + 3] = v.w;
    }
    __syncthreads();
#pragma unroll
    for (int p = 0; p < 2; ++p) {
      const int idx = tid + 256 * p;
      const int nl = idx >> 3, c8 = (idx & 7) * 8;
      unsigned short u[8];
#pragma unroll
      for (int i = 0; i < 8; ++i) u[i] = f2bf(T[(c8 + i) * 65 + nl]);
      *(uint4*)(xT + ((size_t)(b * NTOK_ + n0 + nl)) * CIN_ + c0 + c8) =
          *(uint4*)u;
    }
  } else if (bid < 384) {
    const int t = bid - 256;
    const int which = t >> 5, blk = t & 31;
    const float* src = which == 0 ? WK : which == 1 ? WQ : which == 2 ? WV : Wo;
    unsigned short* dst = which == 0 ? Wkb : which == 1 ? Wqb : which == 2 ? Wvb : Wob;
    const int base = blk * 4096 + tid * 16;
#pragma unroll
    for (int p = 0; p < 4; ++p) {
      const float4 v = *(const float4*)(src + base + p * 4);
      ushort4 u;
      u.x = f2bf(v.x); u.y = f2bf(v.y); u.z = f2bf(v.z); u.w = f2bf(v.w);
      *(ushort4*)(dst + base + p * 4) = u;
    }
  } else {
    for (int i = tid; i < 2 * COUT_; i += 256) stats[i] = 0.f;
  }
}

// ---------------------------------------------------------------------------
// Kernel 1: QKV projection via MFMA. 128f x 128n tile, 4 waves. Frag loads
// just-in-time (w-frags inside the tile loop) to cap register pressure.
// K,Q -> [b][h][n][d] bf16; V (operand-swapped) -> [b][h][d][n] bf16.
// ---------------------------------------------------------------------------
__global__ __launch_bounds__(256) void qkv_kernel(
    const unsigned short* __restrict__ xT, const unsigned short* __restrict__ Wkb,
    const unsigned short* __restrict__ Wqb, const unsigned short* __restrict__ Wvb,
    unsigned short* __restrict__ Kb, unsigned short* __restrict__ Qb,
    unsigned short* __restrict__ Vt) {
  __shared__ unsigned short Wsh[128 * 72];
  __shared__ unsigned short Xsh[128 * 72];
  const int tid = threadIdx.x;
  const int lane = tid & 63, w = tid >> 6;
  const int lx = lane & 15, q = lane >> 4;
  const int wm = w >> 1, wn = w & 1;
  const int n0 = blockIdx.x * 128;
  const int f0 = blockIdx.y * 128;
  const int b = blockIdx.z / 3, which = blockIdx.z % 3;
  const unsigned short* Wb = which == 0 ? Wkb : which == 1 ? Wqb : Wvb;

  const int srow = tid >> 3;
  const int soff = (tid & 7) * 8;
  const unsigned short* Wg = Wb + (size_t)(f0 + srow) * CIN_ + soff;
  const unsigned short* Xg = xT + ((size_t)(b * NTOK_ + n0 + srow)) * CIN_ + soff;

  uint4 wr[4], xr[4];
#pragma unroll
  for (int r = 0; r < 4; ++r) {
    wr[r] = *(const uint4*)(Wg + (size_t)(32 * r) * CIN_);
    xr[r] = *(const uint4*)(Xg + (size_t)(32 * r) * CIN_);
  }

  f32x4 acc[4][4];
#pragma unroll
  for (int i = 0; i < 4; ++i)
#pragma unroll
    for (int j = 0; j < 4; ++j) acc[i][j] = (f32x4){0.f, 0.f, 0.f, 0.f};

  for (int kk = 0; kk < 4; ++kk) {
    __syncthreads();
#pragma unroll
    for (int r = 0; r < 4; ++r) {
      *(uint4*)(Wsh + (srow + 32 * r) * 72 + soff) = wr[r];
      *(uint4*)(Xsh + (srow + 32 * r) * 72 + soff) = xr[r];
    }
    if (kk < 3) {
      const int c0 = (kk + 1) * 64;
#pragma unroll
      for (int r = 0; r < 4; ++r) {
        wr[r] = *(const uint4*)(Wg + (size_t)(32 * r) * CIN_ + c0);
        xr[r] = *(const uint4*)(Xg + (size_t)(32 * r) * CIN_ + c0);
      }
    }
    __syncthreads();
    short8 xF[4][2];
#pragma unroll
    for (int i = 0; i < 4; ++i) {
      xF[i][0] = *(const short8*)(Xsh + (64 * wn + 16 * i + lx) * 72 + q * 8);
      xF[i][1] = *(const short8*)(Xsh + (64 * wn + 16 * i + lx) * 72 + 32 + q * 8);
    }
    if (which < 2) {
#pragma unroll
      for (int i = 0; i < 4; ++i) {
        const short8 w0 = *(const short8*)(Wsh + (64 * wm + 16 * i + lx) * 72 + q * 8);
        const short8 w1 = *(const short8*)(Wsh + (64 * wm + 16 * i + lx) * 72 + 32 + q * 8);
#pragma unroll
        for (int j = 0; j < 4; ++j) {
          acc[i][j] = __builtin_amdgcn_mfma_f32_16x16x32_bf16(w0, xF[j][0], acc[i][j], 0, 0, 0);
          acc[i][j] = __builtin_amdgcn_mfma_f32_16x16x32_bf16(w1, xF[j][1], acc[i][j], 0, 0, 0);
        }
      }
    } else {
#pragma unroll
      for (int j = 0; j < 4; ++j) {
        const short8 w0 = *(const short8*)(Wsh + (64 * wm + 16 * j + lx) * 72 + q * 8);
        const short8 w1 = *(const short8*)(Wsh + (64 * wm + 16 * j + lx) * 72 + 32 + q * 8);
#pragma unroll
        for (int i = 0; i < 4; ++i) {
          acc[i][j] = __builtin_amdgcn_mfma_f32_16x16x32_bf16(xF[i][0], w0, acc[i][j], 0, 0, 0);
          acc[i][j] = __builtin_amdgcn_mfma_f32_16x16x32_bf16(xF[i][1], w1, acc[i][j], 0, 0, 0);
        }
      }
    }
  }

  const int h = (f0 >> 6) + wm;
  if (which < 2) {
    unsigned short* Y = (which == 0 ? Kb : Qb);
#pragma unroll
    for (int i = 0; i < 4; ++i)
#pragma unroll
      for (int j = 0; j < 4; ++j) {
        const int n = n0 + 64 * wn + 16 * j + lx;
        const int d0 = 16 * i + 4 * q;
        ushort4 u;
        u.x = f2bf(acc[i][j][0]); u.y = f2bf(acc[i][j][1]);
        u.z = f2bf(acc[i][j][2]); u.w = f2bf(acc[i][j][3]);
        *(ushort4*)(Y + ((size_t)((b * NH_ + h) * NTOK_ + n)) * DH_ + d0) = u;
      }
  } else {
#pragma unroll
    for (int i = 0; i < 4; ++i)
#pragma unroll
      for (int j = 0; j < 4; ++j) {
        const int d = 16 * j + lx;
        const int n = n0 + 64 * wn + 16 * i + 4 * q;
        ushort4 u;
        u.x = f2bf(acc[i][j][0]); u.y = f2bf(acc[i][j][1]);
        u.z = f2bf(acc[i][j][2]); u.w = f2bf(acc[i][j][3]);
        *(ushort4*)(Vt + ((size_t)((b * NH_ + h) * DH_ + d)) * NTOK_ + n) = u;
      }
  }
}

// ---------------------------------------------------------------------------
// Kernel 2: block-causal attention, split-j (flash-decoding style).
// 1024 blocks = 16 bh x 32 i-tiles x 2 j-chunks. No max-tracking: scores are
// bounded (|S·log2e/16| < ~2), so p = exp2(S·scale) directly; all partials
// share shift 0 -> merge = plain add. Zero cross-lane ops in the loop.
// Partials: Pb[tile][i][d] bf16 (unnormalized O), Lb[tile][i] fp32 (row sums).
// ---------------------------------------------------------------------------
__global__ __launch_bounds__(256) void attn_kernel(
    const unsigned short* __restrict__ Kb, const unsigned short* __restrict__ Qb,
    const unsigned short* __restrict__ Vt, unsigned short* __restrict__ Pb,
    float* __restrict__ Lb) {
  __shared__ __align__(16) char smem[36864];
  unsigned short* Ksh = (unsigned short*)smem;            // [i][d]  64x72
  unsigned short* Qsh = (unsigned short*)(smem + 9216);   // [j][d]  64x72
  unsigned short* Vsh = (unsigned short*)(smem + 18432);  // [d][j]  64x72
  unsigned short* Psh = (unsigned short*)(smem + 27648);  // [i][j]  64x72

  const int tid = threadIdx.x;
  const int lane = tid & 63;
  const int w = tid >> 6;
  const int lx = lane & 15;
  const int q = lane >> 4;

  const int bid = blockIdx.x;          // 0..1023
  const int c = bid & 1;
  const int iblk = (bid >> 1) & 31;
  const int bh = bid >> 6;
  const int h = bh & 7, b = bh >> 3;
  const int i0 = iblk * 64;
  const int njt = ((iblk >> 1) + 1) * 2;
  const int half = njt >> 1;
  const int jt0 = c * half, jt1 = jt0 + half;

  const size_t bhs = (size_t)b * NH_ + h;
  const unsigned short* Kg = Kb + bhs * (size_t)NTOK_ * DH_ + (size_t)i0 * DH_;
  const unsigned short* Qg = Qb + bhs * (size_t)NTOK_ * DH_;
  const unsigned short* Vg = Vt + bhs * (size_t)DH_ * NTOK_;

  const int srow = tid >> 3;
  const int soff = (tid & 7) * 8;

  // stage K tile
#pragma unroll
  for (int r = 0; r < 2; ++r) {
    const int row = srow + 32 * r;
    *(uint4*)(Ksh + row * 72 + soff) = *(const uint4*)(Kg + row * 64 + soff);
  }
  // prefetch first Q/V tiles
  uint4 qr[2], vr[2];
#pragma unroll
  for (int r = 0; r < 2; ++r) {
    const int row = srow + 32 * r;
    qr[r] = *(const uint4*)(Qg + (size_t)(jt0 * 64 + row) * 64 + soff);
    vr[r] = *(const uint4*)(Vg + (size_t)row * NTOK_ + jt0 * 64 + soff);
  }
  __syncthreads();

  const short8 aK0 = *(const short8*)(Ksh + (16 * w + lx) * 72 + q * 8);
  const short8 aK1 = *(const short8*)(Ksh + (16 * w + lx) * 72 + 32 + q * 8);

  f32x4 o[4];       // O^T partial: d=16s+4q+r, i=16w+lx
#pragma unroll
  for (int s = 0; s < 4; ++s) o[s] = (f32x4){0.f, 0.f, 0.f, 0.f};
  float rsum[4] = {0.f, 0.f, 0.f, 0.f};  // per-lane partial row sums

  for (int jt = jt0; jt < jt1; ++jt) {
    __syncthreads();
#pragma unroll
    for (int r = 0; r < 2; ++r) {
      const int row = srow + 32 * r;
      *(uint4*)(Qsh + row * 72 + soff) = qr[r];
      *(uint4*)(Vsh + row * 72 + soff) = vr[r];
    }
    if (jt + 1 < jt1) {
      const int j0n = (jt + 1) * 64;
#pragma unroll
      for (int r = 0; r < 2; ++r) {
        const int row = srow + 32 * r;
        qr[r] = *(const uint4*)(Qg + (size_t)(j0n + row) * 64 + soff);
        vr[r] = *(const uint4*)(Vg + (size_t)row * NTOK_ + j0n + soff);
      }
    }
    __syncthreads();

    // S-phase: S[16i x 64j] per wave (row i=16w+4q+r, col j=16s+lx)
    f32x4 sa[4];
#pragma unroll
    for (int s = 0; s < 4; ++s) {
      sa[s] = (f32x4){0.f, 0.f, 0.f, 0.f};
      const short8 b0 = *(const short8*)(Qsh + (16 * s + lx) * 72 + q * 8);
      const short8 b1 = *(const short8*)(Qsh + (16 * s + lx) * 72 + 32 + q * 8);
      sa[s] = __builtin_amdgcn_mfma_f32_16x16x32_bf16(aK0, b0, sa[s], 0, 0, 0);
      sa[s] = __builtin_amdgcn_mfma_f32_16x16x32_bf16(aK1, b1, sa[s], 0, 0, 0);
    }

    // unshifted exponentials; accumulate per-lane row sums; write P to LDS
#pragma unroll
    for (int s = 0; s < 4; ++s)
#pragma unroll
      for (int r = 0; r < 4; ++r) {
        const float p = __builtin_amdgcn_exp2f(sa[s][r] * SCALE_LOG2_);
        rsum[r] += p;
        Psh[(16 * w + q * 4 + r) * 72 + 16 * s + lx] = f2bf(p);
      }
    asm volatile("s_waitcnt lgkmcnt(0)" ::: "memory");  // own-wave P visible

    // PV^T: O^T[64d x 16i] += V^T[64d x 64j] * P^T[64j x 16i]
    const short8 pb0 = *(const short8*)(Psh + (16 * w + lx) * 72 + q * 8);
    const short8 pb1 = *(const short8*)(Psh + (16 * w + lx) * 72 + 32 + q * 8);
#pragma unroll
    for (int s = 0; s < 4; ++s) {
      const short8 va0 = *(const short8*)(Vsh + (16 * s + lx) * 72 + q * 8);
      const short8 va1 = *(const short8*)(Vsh + (16 * s + lx) * 72 + 32 + q * 8);
      o[s] = __builtin_amdgcn_mfma_f32_16x16x32_bf16(va0, pb0, o[s], 0, 0, 0);
      o[s] = __builtin_amdgcn_mfma_f32_16x16x32_bf16(va1, pb1, o[s], 0, 0, 0);
    }
  }

  // row-sum reduce over the 16 lanes of each q-group (once per chunk)
#pragma unroll
  for (int r = 0; r < 4; ++r) {
#pragma unroll
    for (int off = 1; off < 16; off <<= 1) rsum[r] += __shfl_xor(rsum[r], off);
  }
  if (lx == 0) {
    float4 lv = {rsum[0], rsum[1], rsum[2], rsum[3]};
    *(float4*)(Lb + (size_t)bid * 64 + 16 * w + 4 * q) = lv;
  }
  // store O^T partial as [i][d] bf16: lane's i = 16w+lx, d = 16s+4q+r (contig 4)
  unsigned short* Pt = Pb + (size_t)bid * 4096 + (size_t)(16 * w + lx) * 64;
#pragma unroll
  for (int s = 0; s < 4; ++s) {
    ushort4 u;
    u.x = f2bf(o[s][0]); u.y = f2bf(o[s][1]);
    u.z = f2bf(o[s][2]); u.w = f2bf(o[s][3]);
    *(ushort4*)(Pt + 16 * s + 4 * q) = u;
  }
}

// ---------------------------------------------------------------------------
// Kernel 2b: merge the two j-chunks: O = (P0+P1)/(l0+l1) -> Ob[b][n][f] bf16.
// 512 blocks = 16 bh x 32 i-tiles.
// ---------------------------------------------------------------------------
__global__ __launch_bounds__(256) void merge_kernel(
    const unsigned short* __restrict__ Pb, const float* __restrict__ Lb,
    unsigned short* __restrict__ Ob) {
  __shared__ float linv[64];
  const int k = blockIdx.x;
  const int bh = k >> 5, iblk = k & 31;
  const int h = bh & 7, b = bh >> 3;
  const int i0 = iblk * 64;
  const int tid = threadIdx.x;
  const size_t t0 = (size_t)k * 2, t1 = t0 + 1;
  if (tid < 64) linv[tid] = 1.0f / (Lb[t0 * 64 + tid] + Lb[t1 * 64 + tid]);
  __syncthreads();
  const int dd = (tid & 15) * 4;
#pragma unroll
  for (int p = 0; p < 4; ++p) {
    const int i = (tid >> 4) + p * 16;
    const ushort4 a = *(const ushort4*)(Pb + t0 * 4096 + (size_t)i * 64 + dd);
    const ushort4 c = *(const ushort4*)(Pb + t1 * 4096 + (size_t)i * 64 + dd);
    const float il = linv[i];
    ushort4 u;
    u.x = f2bf((bf2f(a.x) + bf2f(c.x)) * il);
    u.y = f2bf((bf2f(a.y) + bf2f(c.y)) * il);
    u.z = f2bf((bf2f(a.z) + bf2f(c.z)) * il);
    u.w = f2bf((bf2f(a.w) + bf2f(c.w)) * il);
    *(ushort4*)(Ob + ((size_t)(b * NTOK_ + i0 + i)) * FF_ + h * 64 + dd) = u;
  }
}

// ---------------------------------------------------------------------------
// Kernel 3: output projection via MFMA + bias + ReLU + skip -> d_out fp32,
// + BN stats (shuffle-reduced atomics).
// ---------------------------------------------------------------------------
__global__ __launch_bounds__(256) void proj_kernel(
    const unsigned short* __restrict__ Ob, const unsigned short* __restrict__ Wob,
    const float* __restrict__ bo, const float* __restrict__ x,
    float* __restrict__ pre, float* __restrict__ stats) {
  __shared__ unsigned short Osh[64 * 72];
  __shared__ unsigned short Wsh[64 * 72];
  const int tid = threadIdx.x;
  const int lane = tid & 63, w = tid >> 6;
  const int lx = lane & 15, q = lane >> 4;
  const int wn = w & 1, wo = w >> 1;
  const int n0 = blockIdx.x * 64;
  const int o0 = blockIdx.y * 64;
  const int b = blockIdx.z;

  const int srow = tid >> 3;
  const int soff = (tid & 7) * 8;
  const unsigned short* Og = Ob + ((size_t)(b * NTOK_ + n0 + srow)) * FF_ + soff;
  const unsigned short* Wg = Wob + (size_t)(o0 + srow) * FF_ + soff;

  uint4 orr[2], wrr[2];
#pragma unroll
  for (int r = 0; r < 2; ++r) {
    orr[r] = *(const uint4*)(Og + (size_t)(32 * r) * FF_);
    wrr[r] = *(const uint4*)(Wg + (size_t)(32 * r) * FF_);
  }

  f32x4 acc[2][2];
#pragma unroll
  for (int i = 0; i < 2; ++i)
#pragma unroll
    for (int j = 0; j < 2; ++j) acc[i][j] = (f32x4){0.f, 0.f, 0.f, 0.f};

  for (int kk = 0; kk < 8; ++kk) {
    __syncthreads();
#pragma unroll
    for (int r = 0; r < 2; ++r) {
      *(uint4*)(Osh + (srow + 32 * r) * 72 + soff) = orr[r];
      *(uint4*)(Wsh + (srow + 32 * r) * 72 + soff) = wrr[r];
    }
    if (kk < 7) {
      const int c0 = (kk + 1) * 64;
#pragma unroll
      for (int r = 0; r < 2; ++r) {
        orr[r] = *(const uint4*)(Og + (size_t)(32 * r) * FF_ + c0);
        wrr[r] = *(const uint4*)(Wg + (size_t)(32 * r) * FF_ + c0);
      }
    }
    __syncthreads();
    short8 aF[2][2], bF[2][2];
#pragma unroll
    for (int i = 0; i < 2; ++i) {
      aF[i][0] = *(const short8*)(Osh + (32 * wn + 16 * i + lx) * 72 + q * 8);
      aF[i][1] = *(const short8*)(Osh + (32 * wn + 16 * i + lx) * 72 + 32 + q * 8);
      bF[i][0] = *(const short8*)(Wsh + (32 * wo + 16 * i + lx) * 72 + q * 8);
      bF[i][1] = *(const short8*)(Wsh + (32 * wo + 16 * i + lx) * 72 + 32 + q * 8);
    }
#pragma unroll
    for (int i = 0; i < 2; ++i)
#pragma unroll
      for (int j = 0; j < 2; ++j) {
        acc[i][j] = __builtin_amdgcn_mfma_f32_16x16x32_bf16(aF[i][0], bF[j][0], acc[i][j], 0, 0, 0);
        acc[i][j] = __builtin_amdgcn_mfma_f32_16x16x32_bf16(aF[i][1], bF[j][1], acc[i][j], 0, 0, 0);
      }
  }

  float s[2] = {0.f, 0.f}, s2[2] = {0.f, 0.f};
#pragma unroll
  for (int j = 0; j < 2; ++j) {
    const int o = o0 + 32 * wo + 16 * j + lx;
    const float bias = bo[o];
#pragma unroll
    for (int i = 0; i < 2; ++i) {
      const int n = n0 + 32 * wn + 16 * i + 4 * q;
      const float4 xv = *(const float4*)(x + ((size_t)(b * CIN_ + o)) * NTOK_ + n);
      float4 v;
      v.x = fmaxf(acc[i][j][0] + bias, 0.f) + xv.x;
      v.y = fmaxf(acc[i][j][1] + bias, 0.f) + xv.y;
      v.z = fmaxf(acc[i][j][2] + bias, 0.f) + xv.z;
      v.w = fmaxf(acc[i][j][3] + bias, 0.f) + xv.w;
      *(float4*)(pre + ((size_t)(b * COUT_ + o)) * NTOK_ + n) = v;
      s[j] += v.x + v.y + v.z + v.w;
      s2[j] += v.x * v.x + v.y * v.y + v.z * v.z + v.w * v.w;
    }
  }
#pragma unroll
  for (int j = 0; j < 2; ++j) {
    s[j] += __shfl_xor(s[j], 16);  s[j] += __shfl_xor(s[j], 32);
    s2[j] += __shfl_xor(s2[j], 16); s2[j] += __shfl_xor(s2[j], 32);
  }
  if (lane < 16) {
#pragma unroll
    for (int j = 0; j < 2; ++j) {
      const int o = o0 + 32 * wo + 16 * j + lx;
      atomicAdd(&stats[o], s[j]);
      atomicAdd(&stats[COUT_ + o], s2[j]);
    }
  }
}

// ---------------------------------------------------------------------------
// Kernel 4: BatchNorm finalize, in place on d_out.
// ---------------------------------------------------------------------------
__global__ __launch_bounds__(256) void bn_kernel(
    float* __restrict__ out, const float* __restrict__ stats,
    const float* __restrict__ gamma, const float* __restrict__ beta) {
  const int idx = blockIdx.x * 256 + threadIdx.x;
  const int e = idx * 4;
  const int c = (e >> 11) & (COUT_ - 1);
  const float inv = 1.0f / (float)(BB_ * NTOK_);
  const float mean = stats[c] * inv;
  const float var = stats[COUT_ + c] * inv - mean * mean;
  const float sc = rsqrtf(var + BNEPS_) * gamma[c];
  const float bt = beta[c];
  float4 v = *(float4*)(out + e);
  v.x = (v.x - mean) * sc + bt;
  v.y = (v.y - mean) * sc + bt;
  v.z = (v.z - mean) * sc + bt;
  v.w = (v.w - mean) * sc + bt;
  *(float4*)(out + e) = v;
}

extern "C" void kernel_launch(void* const* d_in, const int* in_sizes, int n_in,
                              void* d_out, int out_size, void* d_ws, size_t ws_size,
                              hipStream_t stream) {
  (void)in_sizes; (void)n_in; (void)out_size; (void)ws_size;
  const float* x = (const float*)d_in[0];
  const float* WK = (const float*)d_in[1];
  const float* WQ = (const float*)d_in[2];
  const float* WV = (const float*)d_in[3];
  const float* Wo = (const float*)d_in[4];
  const float* bo = (const float*)d_in[5];
  const float* gamma = (const float*)d_in[6];
  const float* beta = (const float*)d_in[7];

  char* ws = (char*)d_ws;
  unsigned short* xT  = (unsigned short*)(ws);                    // 2 MB
  unsigned short* Wkb = (unsigned short*)(ws + 2097152);          // 256 KB x4
  unsigned short* Wqb = (unsigned short*)(ws + 2359296);
  unsigned short* Wvb = (unsigned short*)(ws + 2621440);
  unsigned short* Wob = (unsigned short*)(ws + 2883584);
  unsigned short* Kb  = (unsigned short*)(ws + 3145728);          // 4 MB
  unsigned short* Qb  = (unsigned short*)(ws + 7340032);          // 4 MB
  unsigned short* Vt  = (unsigned short*)(ws + 11534336);         // 4 MB
  unsigned short* Ob  = (unsigned short*)(ws + 15728640);         // 4 MB
  float* stats        = (float*)(ws + 19922944);                  // 2 KB
  unsigned short* Pb  = (unsigned short*)(ws + 19927040);         // 8.39 MB
  float* Lb           = (float*)(ws + 28315648);                  // 256 KB
  float* out = (float*)d_out;

  prep_kernel<<<385, 256, 0, stream>>>(x, WK, WQ, WV, Wo, xT, Wkb, Wqb, Wvb, Wob, stats);
  qkv_kernel<<<dim3(16, 4, 6), 256, 0, stream>>>(xT, Wkb, Wqb, Wvb, Kb, Qb, Vt);
  attn_kernel<<<dim3(1024, 1, 1), 256, 0, stream>>>(Kb, Qb, Vt, Pb, Lb);
  merge_kernel<<<dim3(512, 1, 1), 256, 0, stream>>>(Pb, Lb, Ob);
  proj_kernel<<<dim3(32, 4, 2), 256, 0, stream>>>(Ob, Wob, bo, x, out, stats);
  bn_kernel<<<1024, 256, 0, stream>>>(out, stats, gamma, beta);
}